// Round 1
// baseline (88.909 us; speedup 1.0000x reference)
//
#include <hip/hip_runtime.h>
#include <math.h>

// Problem constants (from reference setup_inputs)
#define BS 32
#define CH 3
#define HH 512
#define WW 512
#define HWSZ (HH * WW)          // 262144
#define MOMENTUM 0.8
#define EPSILON 1e-5

// ---------------- stats kernel ----------------
// S1[c] = sum_b x[b,c,0,0]
// S2[c] = sum_{b,h,w} x^2
// S3[c] = sum_{b,h,w} x[h,w] * x[(-h)%H, (-w)%W]
constexpr int BLOCKS_PER_PLANE = 8;
constexpr int STAT_THREADS = 256;
constexpr int F4_PER_BLOCK = HWSZ / 4 / BLOCKS_PER_PLANE;   // 8192
constexpr int F4_PER_THREAD = F4_PER_BLOCK / STAT_THREADS;  // 32

__global__ __launch_bounds__(STAT_THREADS) void stats_kernel(
    const float* __restrict__ x, double* __restrict__ sums) {
    const int plane = blockIdx.x / BLOCKS_PER_PLANE;   // 0..95 = b*3+c
    const int blk   = blockIdx.x % BLOCKS_PER_PLANE;
    const int c     = plane % CH;
    const float* __restrict__ base = x + (size_t)plane * HWSZ;
    const int tid = threadIdx.x;

    float s1 = 0.f, s2 = 0.f, s3 = 0.f;
    const int start4 = blk * F4_PER_BLOCK;

#pragma unroll 4
    for (int k = 0; k < F4_PER_THREAD; ++k) {
        const int o4 = start4 + tid + k * STAT_THREADS;
        const int o  = o4 * 4;
        const int h  = o >> 9;        // /512
        const int w  = o & (WW - 1);
        const float4 v = *reinterpret_cast<const float4*>(base + o);
        s2 += v.x * v.x + v.y * v.y + v.z * v.z + v.w * v.w;
        const int hr = (HH - h) & (HH - 1);
        const float* __restrict__ rrow = base + hr * WW;
        // partner cols for w+0..w+3 (contiguous reversed; wave covers the
        // full reversed 1KiB segment across r0..r3 so L1 absorbs the stride)
        const float r0 = rrow[(WW - w)     & (WW - 1)];
        const float r1 = rrow[(WW - w - 1) & (WW - 1)];
        const float r2 = rrow[(WW - w - 2) & (WW - 1)];
        const float r3 = rrow[(WW - w - 3) & (WW - 1)];
        s3 += v.x * r0 + v.y * r1 + v.z * r2 + v.w * r3;
        if (o == 0) s1 += v.x;   // x[b,c,0,0]
    }

    // wave (64-lane) shuffle reduce, then cross-wave via LDS
#pragma unroll
    for (int off = 32; off > 0; off >>= 1) {
        s1 += __shfl_down(s1, off);
        s2 += __shfl_down(s2, off);
        s3 += __shfl_down(s3, off);
    }
    __shared__ float red[3][STAT_THREADS / 64];
    const int lane = tid & 63, wv = tid >> 6;
    if (lane == 0) { red[0][wv] = s1; red[1][wv] = s2; red[2][wv] = s3; }
    __syncthreads();
    if (tid == 0) {
        double t1 = 0.0, t2 = 0.0, t3 = 0.0;
#pragma unroll
        for (int i = 0; i < STAT_THREADS / 64; ++i) {
            t1 += (double)red[0][i];
            t2 += (double)red[1][i];
            t3 += (double)red[2][i];
        }
        atomicAdd(&sums[c * 3 + 0], t1);
        atomicAdd(&sums[c * 3 + 1], t2);
        atomicAdd(&sums[c * 3 + 2], t3);
    }
}

// ---------------- finalize: per-channel scale/shift ----------------
__global__ void finalize_kernel(const double* __restrict__ sums,
                                const float* __restrict__ gamma,
                                const float* __restrict__ beta,
                                const float* __restrict__ rmean,
                                const float* __restrict__ rvar,
                                float* __restrict__ ss) {
    const int c = threadIdx.x;
    if (c >= CH) return;
    const double S1 = sums[c * 3 + 0];
    const double S2 = sums[c * 3 + 1];
    const double S3 = sums[c * 3 + 2];
    const double N = (double)BS * (double)HWSZ;      // bs*H*W
    const double mean = S1 / N;
    const double ex2  = (S2 + S3) / (2.0 * N * (double)HWSZ);  // /(2*bs*H^2*W^2)
    const double var  = ex2 - mean * mean;
    const double rm = (double)rmean[c] * MOMENTUM + (1.0 - MOMENTUM) * mean;
    const double rv = (double)rvar[c]  * MOMENTUM + (1.0 - MOMENTUM) * var;
    const double inv_std = 1.0 / sqrt(rv + EPSILON);
    const float scale = (float)((double)gamma[c] * inv_std);
    const float shift = (float)((double)beta[c] - (double)scale * rm);
    ss[c * 2 + 0] = scale;
    ss[c * 2 + 1] = shift;
}

// ---------------- elementwise normalize ----------------
__global__ __launch_bounds__(256) void norm_kernel(
    const float* __restrict__ x, const float* __restrict__ ss,
    float* __restrict__ out) {
    float sc[CH], sh[CH];
#pragma unroll
    for (int c = 0; c < CH; ++c) { sc[c] = ss[c * 2]; sh[c] = ss[c * 2 + 1]; }
    const int n4 = BS * CH * HWSZ / 4;                // 6,291,456
    const int stride = gridDim.x * blockDim.x;
    for (int i4 = blockIdx.x * blockDim.x + threadIdx.x; i4 < n4; i4 += stride) {
        const int c = (i4 >> 16) % CH;                // plane4 = 65536 f4 per plane
        const float4 v = reinterpret_cast<const float4*>(x)[i4];
        const float s = sc[c], t = sh[c];
        float4 o;
        o.x = fmaf(v.x, s, t);
        o.y = fmaf(v.y, s, t);
        o.z = fmaf(v.z, s, t);
        o.w = fmaf(v.w, s, t);
        reinterpret_cast<float4*>(out)[i4] = o;
    }
}

extern "C" void kernel_launch(void* const* d_in, const int* in_sizes, int n_in,
                              void* d_out, int out_size, void* d_ws, size_t ws_size,
                              hipStream_t stream) {
    const float* x     = (const float*)d_in[0];
    const float* gamma = (const float*)d_in[1];
    const float* beta  = (const float*)d_in[2];
    const float* rmean = (const float*)d_in[3];
    const float* rvar  = (const float*)d_in[4];
    float* out = (float*)d_out;

    double* sums = (double*)d_ws;                     // 9 doubles
    float*  ss   = (float*)((char*)d_ws + 128);       // 6 floats

    hipMemsetAsync(d_ws, 0, 160, stream);
    stats_kernel<<<BS * CH * BLOCKS_PER_PLANE, STAT_THREADS, 0, stream>>>(x, sums);
    finalize_kernel<<<1, 64, 0, stream>>>(sums, gamma, beta, rmean, rvar, ss);
    norm_kernel<<<2048, 256, 0, stream>>>(x, ss, out);
}